// Round 2
// baseline (106.151 us; speedup 1.0000x reference)
//
#include <hip/hip_runtime.h>
#include <stdint.h>

#define EPS 1e-5f

typedef short bf16x8 __attribute__((ext_vector_type(8)));
typedef float f32x4 __attribute__((ext_vector_type(4)));

constexpr int M = 1024, N = 4096, K = 4096;
constexpr int BM = 64, BN = 128, BK = 64;
constexpr int NTK = K / BK;           // 64 K-steps

// prep grid: fixed so regions divide exactly
constexpr int PREP_BLOCKS = 2048;
constexpr int64_t NT = (int64_t)PREP_BLOCKS * 256;      // 524288 threads
constexpr int64_t W4 = (int64_t)N * K / 4;              // 4194304 = 8*NT
constexpr int64_t X4 = (int64_t)M * K / 4;              // 1048576 = 2*NT
constexpr int64_t B4 = N / 4;                           // 1024

static_assert(W4 == 8 * NT, "W region must divide");
static_assert(X4 == 2 * NT, "X region must divide");

// ---------- helpers ----------
__device__ __forceinline__ unsigned short f2bf(float f) {
  union { float f; uint32_t u; } v; v.f = f;
  uint32_t r = (v.u + 0x7fffu + ((v.u >> 16) & 1u)) >> 16;  // RNE
  return (unsigned short)r;
}

__device__ __forceinline__ void gload16(const void* g, void* l) {
  __builtin_amdgcn_global_load_lds(
      (const __attribute__((address_space(1))) void*)(uintptr_t)g,
      (__attribute__((address_space(3))) void*)(uintptr_t)l, 16, 0, 0);
}

// ---------- prep v2: branch-free regions, 4-wide load batches ----------
__global__ __launch_bounds__(256) void prep_kernel(
    const float* __restrict__ wm, const float* __restrict__ wsp,
    const float* __restrict__ nw, const float* __restrict__ bm,
    const float* __restrict__ bsp, const float* __restrict__ nb,
    const float* __restrict__ x,
    unsigned short* __restrict__ w_bf, unsigned short* __restrict__ x_bf,
    float* __restrict__ bias)
{
  const int64_t t = (int64_t)blockIdx.x * 256 + threadIdx.x;  // 0..NT-1
  const float4* wm4  = (const float4*)wm;
  const float4* wsp4 = (const float4*)wsp;
  const float4* nw4  = (const float4*)nw;
  const float4* x4   = (const float4*)x;
  ushort4* wb4 = (ushort4*)w_bf;
  ushort4* xb4 = (ushort4*)x_bf;

  // ---- W region: 8 float4 per thread, 2 batches of 4 (12 loads in flight) ----
#pragma unroll
  for (int b = 0; b < 2; ++b) {
    float4 a[4], s[4], n[4];
#pragma unroll
    for (int j = 0; j < 4; ++j) {
      const int64_t i = t + (int64_t)(b * 4 + j) * NT;
      a[j] = wm4[i]; s[j] = wsp4[i]; n[j] = nw4[i];
    }
#pragma unroll
    for (int j = 0; j < 4; ++j) {
      ushort4 o;
      o.x = f2bf(a[j].x + n[j].x * fmaxf(__expf(s[j].x), EPS));
      o.y = f2bf(a[j].y + n[j].y * fmaxf(__expf(s[j].y), EPS));
      o.z = f2bf(a[j].z + n[j].z * fmaxf(__expf(s[j].z), EPS));
      o.w = f2bf(a[j].w + n[j].w * fmaxf(__expf(s[j].w), EPS));
      wb4[t + (int64_t)(b * 4 + j) * NT] = o;
    }
  }

  // ---- X region: 2 float4 per thread ----
  {
    float4 v0 = x4[t];
    float4 v1 = x4[t + NT];
    ushort4 o0, o1;
    o0.x = f2bf(v0.x); o0.y = f2bf(v0.y); o0.z = f2bf(v0.z); o0.w = f2bf(v0.w);
    o1.x = f2bf(v1.x); o1.y = f2bf(v1.y); o1.z = f2bf(v1.z); o1.w = f2bf(v1.w);
    xb4[t]      = o0;
    xb4[t + NT] = o1;
  }

  // ---- bias region: first B4 threads ----
  if (t < B4) {
    float4 a = ((const float4*)bm)[t];
    float4 s = ((const float4*)bsp)[t];
    float4 n = ((const float4*)nb)[t];
    float4 o;
    o.x = a.x + n.x * fmaxf(__expf(s.x), EPS);
    o.y = a.y + n.y * fmaxf(__expf(s.y), EPS);
    o.z = a.z + n.z * fmaxf(__expf(s.z), EPS);
    o.w = a.w + n.w * fmaxf(__expf(s.w), EPS);
    ((float4*)bias)[t] = o;
  }
}

// ---------- GEMM: out = x_bf @ w_bf^T + bias (unchanged from R1) ----------
__global__ __launch_bounds__(256) void gemm_kernel(
    const unsigned short* __restrict__ Abf,
    const unsigned short* __restrict__ Bbf,
    const float* __restrict__ bias,
    float* __restrict__ out)
{
  __shared__ unsigned short lds_mem[2][(BM + BN) * BK];  // 48 KB

  const int nwg = gridDim.x;
  const int bid = blockIdx.x;
  const int lid = (bid % 8) * (nwg / 8) + bid / 8;
  const int bc = lid >> 4;   // N-tile, 0..31
  const int br = lid & 15;   // M-tile, 0..15

  const int tid = threadIdx.x;
  const int lane = tid & 63;
  const int wid = tid >> 6;

  const int srow = wid * 8 + (lane >> 3);
  const int scol = (lane & 7) * 8;
  const unsigned short* gA = Abf + (int64_t)(br * BM + srow) * K + scol;
  const unsigned short* gB = Bbf + (int64_t)(bc * BN + srow) * K + scol;

  unsigned short* ldsA0 = &lds_mem[0][0];
  unsigned short* ldsB0 = &lds_mem[0][BM * BK];
  unsigned short* ldsA1 = &lds_mem[1][0];
  unsigned short* ldsB1 = &lds_mem[1][BM * BK];
  const int woff = wid * 8 * BK;

  auto stage = [&](int b, int t) {
    const unsigned short* ga = gA + t * BK;
    const unsigned short* gb = gB + t * BK;
    unsigned short* la = (b ? ldsA1 : ldsA0) + woff;
    unsigned short* lb = (b ? ldsB1 : ldsB0) + woff;
    gload16(ga,          la);
    gload16(ga + 32 * K, la + 32 * BK);
    gload16(gb,          lb);
    gload16(gb + 32 * K, lb + 32 * BK);
    gload16(gb + 64 * K, lb + 64 * BK);
    gload16(gb + 96 * K, lb + 96 * BK);
  };

  f32x4 acc[2][4] = {};
  const int fr = lane & 15;
  const int fk = (lane >> 4) << 3;
  const int am = (wid >> 1) * 32;
  const int an = (wid & 1) * 64;

  stage(0, 0);

  int cur = 0;
  for (int t = 0; t < NTK; ++t) {
    __syncthreads();
    if (t + 1 < NTK) stage(cur ^ 1, t + 1);
    const unsigned short* lA = cur ? ldsA1 : ldsA0;
    const unsigned short* lB = cur ? ldsB1 : ldsB0;
#pragma unroll
    for (int kk = 0; kk < 2; ++kk) {
      const int ko = kk * 32 + fk;
      bf16x8 a0 = *(const bf16x8*)&lA[(am +  0 + fr) * BK + ko];
      bf16x8 a1 = *(const bf16x8*)&lA[(am + 16 + fr) * BK + ko];
      bf16x8 b0 = *(const bf16x8*)&lB[(an +  0 + fr) * BK + ko];
      bf16x8 b1 = *(const bf16x8*)&lB[(an + 16 + fr) * BK + ko];
      bf16x8 b2 = *(const bf16x8*)&lB[(an + 32 + fr) * BK + ko];
      bf16x8 b3 = *(const bf16x8*)&lB[(an + 48 + fr) * BK + ko];
      acc[0][0] = __builtin_amdgcn_mfma_f32_16x16x32_bf16(a0, b0, acc[0][0], 0, 0, 0);
      acc[0][1] = __builtin_amdgcn_mfma_f32_16x16x32_bf16(a0, b1, acc[0][1], 0, 0, 0);
      acc[0][2] = __builtin_amdgcn_mfma_f32_16x16x32_bf16(a0, b2, acc[0][2], 0, 0, 0);
      acc[0][3] = __builtin_amdgcn_mfma_f32_16x16x32_bf16(a0, b3, acc[0][3], 0, 0, 0);
      acc[1][0] = __builtin_amdgcn_mfma_f32_16x16x32_bf16(a1, b0, acc[1][0], 0, 0, 0);
      acc[1][1] = __builtin_amdgcn_mfma_f32_16x16x32_bf16(a1, b1, acc[1][1], 0, 0, 0);
      acc[1][2] = __builtin_amdgcn_mfma_f32_16x16x32_bf16(a1, b2, acc[1][2], 0, 0, 0);
      acc[1][3] = __builtin_amdgcn_mfma_f32_16x16x32_bf16(a1, b3, acc[1][3], 0, 0, 0);
    }
    cur ^= 1;
  }

  const int orow0 = br * BM + am + (lane >> 4) * 4;
  const int ocol0 = bc * BN + an + fr;
#pragma unroll
  for (int i = 0; i < 2; ++i) {
#pragma unroll
    for (int j = 0; j < 4; ++j) {
      const int col = ocol0 + j * 16;
      const float bv = bias[col];
      const int row = orow0 + i * 16;
#pragma unroll
      for (int r = 0; r < 4; ++r)
        out[(int64_t)(row + r) * N + col] = acc[i][j][r] + bv;
    }
  }
}

// ---------- correctness fallback if workspace too small ----------
__global__ __launch_bounds__(256) void fallback_kernel(
    const float* __restrict__ x, const float* __restrict__ wm,
    const float* __restrict__ wsp, const float* __restrict__ bm,
    const float* __restrict__ bsp, const float* __restrict__ nw,
    const float* __restrict__ nb, float* __restrict__ out)
{
  int64_t idx = (int64_t)blockIdx.x * 256 + threadIdx.x;
  if (idx >= (int64_t)M * N) return;
  int b = (int)(idx >> 12);
  int o = (int)(idx & (N - 1));
  const float* xr = x + (int64_t)b * K;
  const float* wmr = wm + (int64_t)o * K;
  const float* wsr = wsp + (int64_t)o * K;
  const float* nwr = nw + (int64_t)o * K;
  float s = 0.f;
  for (int k = 0; k < K; ++k)
    s += xr[k] * (wmr[k] + nwr[k] * fmaxf(__expf(wsr[k]), EPS));
  out[idx] = s + bm[o] + nb[o] * fmaxf(__expf(bsp[o]), EPS);
}

extern "C" void kernel_launch(void* const* d_in, const int* in_sizes, int n_in,
                              void* d_out, int out_size, void* d_ws, size_t ws_size,
                              hipStream_t stream) {
  const float* x   = (const float*)d_in[0];
  const float* wm  = (const float*)d_in[1];
  const float* wsp = (const float*)d_in[2];
  const float* bm  = (const float*)d_in[3];
  const float* bsp = (const float*)d_in[4];
  const float* nw  = (const float*)d_in[5];
  const float* nb  = (const float*)d_in[6];
  float* out = (float*)d_out;

  const size_t w_bytes = (size_t)N * K * 2;
  const size_t x_bytes = (size_t)M * K * 2;
  const size_t b_bytes = (size_t)N * 4;
  if (ws_size < w_bytes + x_bytes + b_bytes) {
    fallback_kernel<<<(int)(((int64_t)M * N + 255) / 256), 256, 0, stream>>>(
        x, wm, wsp, bm, bsp, nw, nb, out);
    return;
  }

  char* ws = (char*)d_ws;
  unsigned short* w_bf = (unsigned short*)ws;
  unsigned short* x_bf = (unsigned short*)(ws + w_bytes);
  float* bias = (float*)(ws + w_bytes + x_bytes);

  prep_kernel<<<PREP_BLOCKS, 256, 0, stream>>>(wm, wsp, nw, bm, bsp, nb, x, w_bf, x_bf, bias);
  gemm_kernel<<<(M / BM) * (N / BN), 256, 0, stream>>>(x_bf, w_bf, bias, out);
}